// Round 1
// 9068.798 us; speedup vs baseline: 1.0931x; 1.0931x over previous
//
#include <hip/hip_runtime.h>

typedef __bf16 bf16;
typedef __attribute__((ext_vector_type(8))) __bf16 bf16x8;
typedef __attribute__((ext_vector_type(4))) __bf16 bf16x4;
typedef __attribute__((ext_vector_type(2))) __bf16 bf16x2;
typedef __attribute__((ext_vector_type(4))) float f32x4;

#define N_NODES 100000
#define N_EDGES 3200000

struct CvtDesc {
    const void* src[23];
    unsigned long long pre[24];
};

// ------------------------------------------------ input dtype detection
// adj_vals = uniform[0,1/32] >= 0. bf16-packed: bit15 of each u32 word is a
// sign bit == 0. fp32: bit15 is a random mantissa bit. Any set bit -> fp32.
__global__ void detect_kernel(const unsigned int* __restrict__ w, int* flag) {
    unsigned int v = w[threadIdx.x];                 // 64 threads, one wave
    unsigned long long b = __ballot(((v >> 15) & 1u) != 0u);
    if (threadIdx.x == 0) flag[0] = (b != 0ull) ? 1 : 0;
}

// ------------------------------------- convert/copy all float inputs to bf16
__global__ __launch_bounds__(256) void cvt_all(CvtDesc d, bf16* __restrict__ dst,
                                               const int* __restrict__ flag, long total) {
    int f = *flag;
    for (long i = (long)blockIdx.x * 256 + threadIdx.x; i < total; i += (long)gridDim.x * 256) {
        int lo = 0, hi = 22;
        while (lo < hi) { int mid = (lo + hi + 1) >> 1; if (i >= (long)d.pre[mid]) lo = mid; else hi = mid - 1; }
        long k = i - (long)d.pre[lo];
        if (f) dst[i] = (bf16)((const float*)d.src[lo])[k];
        else   dst[i] = ((const bf16*)d.src[lo])[k];
    }
}

// ---------------------------------------------------------------- CSR build
__global__ void hist_kernel(const int* __restrict__ rows, int* __restrict__ cnt, int E) {
    int e = blockIdx.x * 256 + threadIdx.x;
    if (e < E) atomicAdd(&cnt[rows[e]], 1);
}

// device-wide exclusive scan, 3 kernels (n = 100000 -> 98 blocks of 1024)
__global__ __launch_bounds__(1024) void scan1_kernel(const int* __restrict__ cnt,
                                                     int* __restrict__ excl,
                                                     int* __restrict__ blksum, int n) {
    __shared__ int wsum[16];
    int tid = threadIdx.x;
    int i = blockIdx.x * 1024 + tid;
    int lane = tid & 63, w = tid >> 6;
    int v = (i < n) ? cnt[i] : 0;
    int x = v;
#pragma unroll
    for (int off = 1; off < 64; off <<= 1) {
        int t = __shfl_up(x, off);
        if (lane >= off) x += t;
    }
    if (lane == 63) wsum[w] = x;
    __syncthreads();
    if (w == 0 && lane < 16) {
        int s = wsum[lane];
#pragma unroll
        for (int off = 1; off < 16; off <<= 1) {
            int t = __shfl_up(s, off);
            if (lane >= off) s += t;
        }
        wsum[lane] = s;
    }
    __syncthreads();
    int base = (w > 0) ? wsum[w - 1] : 0;
    int incl = base + x;
    if (i < n) excl[i] = incl - v;
    if (tid == 1023) blksum[blockIdx.x] = incl;
}

__global__ __launch_bounds__(128) void scan2_kernel(int* __restrict__ blksum, int nb,
                                                    int* __restrict__ totalp) {
    __shared__ int sh[128];
    int tid = threadIdx.x;
    int v = (tid < nb) ? blksum[tid] : 0;
    sh[tid] = v;
    __syncthreads();
    for (int off = 1; off < 128; off <<= 1) {
        int t = (tid >= off) ? sh[tid - off] : 0;
        __syncthreads();
        sh[tid] += t;
        __syncthreads();
    }
    if (tid < nb) blksum[tid] = sh[tid] - v;   // exclusive
    if (tid == 127) *totalp = sh[127];
}

__global__ __launch_bounds__(1024) void scan3_kernel(int* __restrict__ row_start,
                                                     const int* __restrict__ blksum,
                                                     int* __restrict__ fill, int n) {
    int i = blockIdx.x * 1024 + threadIdx.x;
    if (i < n) {
        int r = row_start[i] + blksum[blockIdx.x];
        row_start[i] = r;
        fill[i] = r;
    }
}

__global__ void scatter_kernel(const int* __restrict__ rows, const int* __restrict__ cols,
                               const void* __restrict__ vals, int* __restrict__ fill,
                               int* __restrict__ csr_col, bf16* __restrict__ csr_val,
                               const int* __restrict__ flag, int E) {
    int e = blockIdx.x * 256 + threadIdx.x;
    if (e < E) {
        int r = rows[e];
        int p = atomicAdd(&fill[r], 1);
        csr_col[p] = cols[e];
        float v = (*flag) ? ((const float*)vals)[e] : (float)((const bf16*)vals)[e];
        csr_val[p] = (bf16)v;
    }
}

// ------------------------------------------------------------ MFMA bf16 GEMM
// C = act(A @ B + bias); optional combine 0.5*val+0.5*comb (comb may alias C).
// If Cf != null and *flagp: store fp32 to Cf instead of bf16 to C.
__global__ __launch_bounds__(256) void gemm_kernel(
    const bf16* __restrict__ A, const bf16* __restrict__ B,
    bf16* C, float* Cf, const bf16* __restrict__ bias, const bf16* comb,
    const int* __restrict__ flagp, int M, int K, int N, int do_relu)
{
    __shared__ bf16 As[128][40];
    __shared__ bf16 Bs[128][40];

    int tid  = threadIdx.x;
    int lane = tid & 63;
    int wave = tid >> 6;
    int wm = (wave >> 1) * 64;
    int wn = (wave & 1) * 64;
    int lm = lane & 15;
    int k8 = (lane >> 4) * 8;
    long row0 = (long)blockIdx.y * 128;
    int  col0 = blockIdx.x * 128;

    f32x4 zero4 = {0.f, 0.f, 0.f, 0.f};
    f32x4 acc[4][4];
#pragma unroll
    for (int i = 0; i < 4; i++)
#pragma unroll
        for (int j = 0; j < 4; j++) acc[i][j] = zero4;

    for (int k0 = 0; k0 < K; k0 += 32) {
#pragma unroll
        for (int c = 0; c < 2; c++) {
            int ch = tid + c * 256;
            int m  = ch >> 2;
            int kc = (ch & 3) << 3;
            long gm = row0 + m;
            int  gk = k0 + kc;
            if (gm < M && gk + 8 <= K) {
                const bf16* p = A + gm * (long)K + gk;
                unsigned long long v0 = *(const unsigned long long*)p;
                unsigned long long v1 = *(const unsigned long long*)(p + 4);
                *(unsigned long long*)&As[m][kc]     = v0;
                *(unsigned long long*)&As[m][kc + 4] = v1;
            } else {
#pragma unroll
                for (int j = 0; j < 8; j++) {
                    bf16 v = (bf16)0.f;
                    if (gm < M && gk + j < K) v = A[gm * (long)K + gk + j];
                    As[m][kc + j] = v;
                }
            }
        }
        {
            int n   = tid & 127;
            int kb0 = (tid >> 7) * 8;
            int gcol = col0 + n;
#pragma unroll
            for (int h = 0; h < 2; h++) {
                int kb = kb0 + h * 16;
                bf16x8 t;
#pragma unroll
                for (int j = 0; j < 8; j++) {
                    int gk = k0 + kb + j;
                    bf16 v = (bf16)0.f;
                    if (gk < K && gcol < N) v = B[(long)gk * N + gcol];
                    t[j] = v;
                }
                *(bf16x8*)&Bs[n][kb] = t;
            }
        }
        __syncthreads();

        bf16x8 af[4], bfr[4];
#pragma unroll
        for (int i = 0; i < 4; i++) af[i]  = *(const bf16x8*)&As[wm + i * 16 + lm][k8];
#pragma unroll
        for (int j = 0; j < 4; j++) bfr[j] = *(const bf16x8*)&Bs[wn + j * 16 + lm][k8];
#pragma unroll
        for (int i = 0; i < 4; i++)
#pragma unroll
            for (int j = 0; j < 4; j++)
                acc[i][j] = __builtin_amdgcn_mfma_f32_16x16x32_bf16(af[i], bfr[j], acc[i][j], 0, 0, 0);
        __syncthreads();
    }

    int f32o = (Cf != nullptr) && (*flagp != 0);
#pragma unroll
    for (int i = 0; i < 4; i++) {
#pragma unroll
        for (int r = 0; r < 4; r++) {
            long row = row0 + wm + i * 16 + (lane >> 4) * 4 + r;
            if (row < M) {
#pragma unroll
                for (int j = 0; j < 4; j++) {
                    int col = col0 + wn + j * 16 + lm;
                    if (col < N) {
                        float v = acc[i][j][r];
                        if (bias) v += (float)bias[col];
                        if (do_relu) v = fmaxf(v, 0.f);
                        if (comb) v = 0.5f * v + 0.5f * (float)comb[row * (long)N + col];
                        if (f32o) Cf[row * (long)N + col] = v;
                        else      C [row * (long)N + col] = (bf16)v;
                    }
                }
            }
        }
    }
}

// ----------------------------------------------------- spmm, D=500 (bf16 io)
// one row per WAVE: lane l covers elems {4l..4l+3} and {256+4l..256+4l+3}.
// Rows are 1000 B (8-byte aligned) -> bf16x4 (dwordx2) loads are safe.
// 4-edge unroll keeps 8 x 512B wave-loads in flight (was 2 x 128B).
__global__ __launch_bounds__(256) void spmm500_kernel(
    const int* __restrict__ row_start, const int* __restrict__ csr_col,
    const bf16* __restrict__ csr_val, const bf16* __restrict__ Min,
    bf16* __restrict__ Mout, int n_rows)
{
    int wave = threadIdx.x >> 6;
    int lane = threadIdx.x & 63;
    int row  = blockIdx.x * 4 + wave;
    if (row >= n_rows) return;
    int s = row_start[row], e = row_start[row + 1];

    int o0 = lane * 4;          // elems 0..255 (all 64 lanes)
    int o1 = 256 + lane * 4;    // elems 256..499 (lanes 0..60; >=61 loads junk, never stored)

    float acc[8];
#pragma unroll
    for (int q = 0; q < 8; q++) acc[q] = 0.f;

    for (int base = s; base < e; base += 64) {
        int cnt = e - base; if (cnt > 64) cnt = 64;
        int idx = base + lane;
        int   cl = (idx < e) ? csr_col[idx] : 0;
        float vl = (idx < e) ? (float)csr_val[idx] : 0.f;

        int j = 0;
        for (; j + 4 <= cnt; j += 4) {
            int   c0 = __shfl(cl, j),     c1 = __shfl(cl, j + 1);
            int   c2 = __shfl(cl, j + 2), c3 = __shfl(cl, j + 3);
            float v0 = __shfl(vl, j),     v1 = __shfl(vl, j + 1);
            float v2 = __shfl(vl, j + 2), v3 = __shfl(vl, j + 3);
            const bf16* m0 = Min + (long)c0 * 500;
            const bf16* m1 = Min + (long)c1 * 500;
            const bf16* m2 = Min + (long)c2 * 500;
            const bf16* m3 = Min + (long)c3 * 500;
            bf16x4 a0 = *(const bf16x4*)(m0 + o0), b0 = *(const bf16x4*)(m0 + o1);
            bf16x4 a1 = *(const bf16x4*)(m1 + o0), b1 = *(const bf16x4*)(m1 + o1);
            bf16x4 a2 = *(const bf16x4*)(m2 + o0), b2 = *(const bf16x4*)(m2 + o1);
            bf16x4 a3 = *(const bf16x4*)(m3 + o0), b3 = *(const bf16x4*)(m3 + o1);
#pragma unroll
            for (int q = 0; q < 4; q++) {
                acc[q]     += v0 * (float)a0[q];
                acc[4 + q] += v0 * (float)b0[q];
            }
#pragma unroll
            for (int q = 0; q < 4; q++) {
                acc[q]     += v1 * (float)a1[q];
                acc[4 + q] += v1 * (float)b1[q];
            }
#pragma unroll
            for (int q = 0; q < 4; q++) {
                acc[q]     += v2 * (float)a2[q];
                acc[4 + q] += v2 * (float)b2[q];
            }
#pragma unroll
            for (int q = 0; q < 4; q++) {
                acc[q]     += v3 * (float)a3[q];
                acc[4 + q] += v3 * (float)b3[q];
            }
        }
        for (; j < cnt; ++j) {
            int   c = __shfl(cl, j);
            float v = __shfl(vl, j);
            const bf16* mr = Min + (long)c * 500;
            bf16x4 a = *(const bf16x4*)(mr + o0);
            bf16x4 b = *(const bf16x4*)(mr + o1);
#pragma unroll
            for (int q = 0; q < 4; q++) {
                acc[q]     += v * (float)a[q];
                acc[4 + q] += v * (float)b[q];
            }
        }
    }

    bf16* orow = Mout + (long)row * 500;
    bf16x4 out0;
#pragma unroll
    for (int q = 0; q < 4; q++) out0[q] = (bf16)acc[q];
    *(bf16x4*)(orow + o0) = out0;
    if (lane < 61) {
        bf16x4 out1;
#pragma unroll
        for (int q = 0; q < 4; q++) out1[q] = (bf16)acc[4 + q];
        *(bf16x4*)(orow + o1) = out1;
    }
}

// -------------------------------------------------------- spmm, D=10 (f32 io)
__global__ __launch_bounds__(256) void spmm10_kernel(
    const int* __restrict__ row_start, const int* __restrict__ csr_col,
    const bf16* __restrict__ csr_val, const float* __restrict__ Tin,
    float* __restrict__ Tout, int n_rows)
{
    int row  = blockIdx.x * 4 + (threadIdx.x >> 6);
    int lane = threadIdx.x & 63;
    if (row >= n_rows) return;
    int s = row_start[row], e = row_start[row + 1];
    float acc[10];
#pragma unroll
    for (int d = 0; d < 10; d++) acc[d] = 0.f;
    for (int i = s + lane; i < e; i += 64) {
        int c = csr_col[i];
        float v = (float)csr_val[i];
        const float2* tr = (const float2*)(Tin + (long)c * 10);   // 8B-aligned (c*40)
        float2 p0 = tr[0], p1 = tr[1], p2 = tr[2], p3 = tr[3], p4 = tr[4];
        acc[0] += v * p0.x; acc[1] += v * p0.y;
        acc[2] += v * p1.x; acc[3] += v * p1.y;
        acc[4] += v * p2.x; acc[5] += v * p2.y;
        acc[6] += v * p3.x; acc[7] += v * p3.y;
        acc[8] += v * p4.x; acc[9] += v * p4.y;
    }
#pragma unroll
    for (int off = 32; off; off >>= 1)
#pragma unroll
        for (int d = 0; d < 10; d++) acc[d] += __shfl_down(acc[d], off);
    if (lane == 0) {
#pragma unroll
        for (int d = 0; d < 10; d++) Tout[(long)row * 10 + d] = acc[d];
    }
}

// --------------------------------- A[M,K](bf16) @ W[K,10](bf16): wave per row
__global__ __launch_bounds__(256) void rowgemm10_kernel(
    const bf16* __restrict__ A, const bf16* __restrict__ W,
    const bf16* __restrict__ bias, float* outf, bf16* outb, float* outbf,
    const int* __restrict__ flagp, int n_rows, int K)
{
    int row  = blockIdx.x * 4 + (threadIdx.x >> 6);
    int lane = threadIdx.x & 63;
    if (row >= n_rows) return;
    const bf16* a = A + (long)row * K;
    float acc[10];
#pragma unroll
    for (int j = 0; j < 10; j++) acc[j] = 0.f;
    for (int k = lane * 4; k + 3 < K; k += 256) {    // K % 4 == 0 (2000)
        bf16x4 av = *(const bf16x4*)(a + k);         // row*2K and k*2 both 8B-aligned
#pragma unroll
        for (int q = 0; q < 4; q++) {
            float v = (float)av[q];
            const bf16x2* w = (const bf16x2*)(W + (long)(k + q) * 10);  // 4B-aligned
#pragma unroll
            for (int h = 0; h < 5; h++) {
                bf16x2 wp = w[h];
                acc[2 * h]     += v * (float)wp[0];
                acc[2 * h + 1] += v * (float)wp[1];
            }
        }
    }
#pragma unroll
    for (int off = 32; off; off >>= 1)
#pragma unroll
        for (int j = 0; j < 10; j++) acc[j] += __shfl_down(acc[j], off);
    if (lane == 0) {
        int f = (outb != nullptr) && (*flagp != 0);
#pragma unroll
        for (int j = 0; j < 10; j++) {
            float r = acc[j] + (bias ? (float)bias[j] : 0.f);
            if (outf) outf[(long)row * 10 + j] = r;
            if (outb) {
                if (f) outbf[(long)row * 10 + j] = r;
                else   outb [(long)row * 10 + j] = (bf16)r;
            }
        }
    }
}

// ----------------------------- d1 = relu(z[rows,10] @ W[10,2000] + b)
// 4 outputs per thread, vectorized W loads/stores.
__global__ void dec1_kernel(const float* __restrict__ z, const bf16* __restrict__ W,
                            const bf16* __restrict__ b, bf16* __restrict__ d1,
                            int row_off, int Dout)
{
    int row = blockIdx.x;
    int c0 = (blockIdx.y * 256 + threadIdx.x) * 4;
    if (c0 + 3 >= Dout) return;                       // Dout % 4 == 0
    const float* zr = z + (long)(row_off + row) * 10;
    bf16x4 bb = *(const bf16x4*)(b + c0);
    float acc[4];
#pragma unroll
    for (int q = 0; q < 4; q++) acc[q] = (float)bb[q];
#pragma unroll
    for (int k = 0; k < 10; k++) {
        float zv = zr[k];
        bf16x4 wv = *(const bf16x4*)(W + (long)k * Dout + c0);
#pragma unroll
        for (int q = 0; q < 4; q++) acc[q] += zv * (float)wv[q];
    }
    bf16x4 o;
#pragma unroll
    for (int q = 0; q < 4; q++) o[q] = (bf16)fmaxf(acc[q], 0.f);
    *(bf16x4*)(d1 + (long)row * Dout + c0) = o;
}

// ------------- t5 = (0.5*relu(s4) + 0.5*z) @ g5[10,10]
__global__ void t5_kernel(const float* __restrict__ s4, const float* __restrict__ z,
                          const bf16* __restrict__ g5, float* __restrict__ t5, int n)
{
    int row = blockIdx.x * 256 + threadIdx.x;
    if (row >= n) return;
    float c5[10];
#pragma unroll
    for (int k = 0; k < 10; k++)
        c5[k] = 0.5f * fmaxf(s4[(long)row * 10 + k], 0.f) + 0.5f * z[(long)row * 10 + k];
#pragma unroll
    for (int j = 0; j < 10; j++) {
        float a = 0.f;
#pragma unroll
        for (int k = 0; k < 10; k++) a += c5[k] * (float)g5[k * 10 + j];
        t5[(long)row * 10 + j] = a;
    }
}

__global__ void softmax10_kernel(const float* __restrict__ S, bf16* Pb, float* Pf,
                                 const int* __restrict__ flagp, int n) {
    int row = blockIdx.x * 256 + threadIdx.x;
    if (row >= n) return;
    float v[10];
    float m = -1e30f;
#pragma unroll
    for (int j = 0; j < 10; j++) { v[j] = S[(long)row * 10 + j]; m = fmaxf(m, v[j]); }
    float sum = 0.f;
#pragma unroll
    for (int j = 0; j < 10; j++) { v[j] = expf(v[j] - m); sum += v[j]; }
    float inv = 1.f / sum;
    int f = *flagp;
#pragma unroll
    for (int j = 0; j < 10; j++) {
        if (f) Pf[(long)row * 10 + j] = v[j] * inv;
        else   Pb[(long)row * 10 + j] = (bf16)(v[j] * inv);
    }
}

__global__ void q_kernel(const float* __restrict__ z, const bf16* __restrict__ cluster,
                         bf16* qb, float* qf, const int* __restrict__ flagp, int n) {
    int row = blockIdx.x * 256 + threadIdx.x;
    if (row >= n) return;
    float zr[10];
#pragma unroll
    for (int d = 0; d < 10; d++) zr[d] = z[(long)row * 10 + d];
    float q[10]; float s = 0.f;
#pragma unroll
    for (int k = 0; k < 10; k++) {
        float dist = 0.f;
#pragma unroll
        for (int d = 0; d < 10; d++) {
            float df = zr[d] - (float)cluster[k * 10 + d];
            dist += df * df;
        }
        q[k] = 1.f / (1.f + dist);   // v=1, exponent (v+1)/2 = 1
        s += q[k];
    }
    float inv = 1.f / s;
    int f = *flagp;
#pragma unroll
    for (int k = 0; k < 10; k++) {
        if (f) qf[(long)row * 10 + k] = q[k] * inv;
        else   qb[(long)row * 10 + k] = (bf16)(q[k] * inv);
    }
}

__global__ void canary_kernel(bf16* o, float v) {
    if (threadIdx.x == 0 && blockIdx.x == 0) o[0] = (bf16)v;
}

// ---------------------------------------------------------------------------
extern "C" void kernel_launch(void* const* d_in, const int* in_sizes, int n_in,
                              void* d_out, int out_size, void* d_ws, size_t ws_size,
                              hipStream_t stream)
{
    const int*  arows  = (const int*)d_in[1];
    const int*  acols  = (const int*)d_in[2];
    const void* avals  = d_in[3];

    // float-input index map (all except adj_rows/cols/vals)
    const int fidx[23] = {0,4,5,6,7,8,9,10,11,12,13,14,15,16,17,18,19,20,21,22,23,24,25};
    CvtDesc cd;
    unsigned long long tot = 0;
    for (int a = 0; a < 23; a++) {
        cd.src[a] = d_in[fidx[a]];
        cd.pre[a] = tot;
        tot += (unsigned long long)in_sizes[fidx[a]];
    }
    cd.pre[23] = tot;

    // output views (element offsets identical in both dtypes)
    bf16*  outB = (bf16*)d_out;
    float* outF = (float*)d_out;
    size_t oq = (size_t)N_NODES * 500, op = oq + (size_t)N_NODES * 10, oz = op + (size_t)N_NODES * 10;
    bf16* cbuf = outB;   // h1 -> c2 -> c3 scratch in the x_bar region (dead until decoder)

    // ---- workspace fit
    auto pad = [](size_t b) { return (b + 255) & ~(size_t)255; };
    size_t fixed = 0;
    fixed += pad(256);                            // flag
    fixed += pad((size_t)(N_NODES + 1) * 4);      // row_start
    fixed += pad((size_t)N_NODES * 4);            // row_fill
    fixed += pad(1024);                           // blksum
    fixed += pad((size_t)N_EDGES * 4);            // csr_col
    fixed += pad((size_t)N_EDGES * 2);            // csr_val
    fixed += pad((size_t)N_NODES * 500 * 2);      // h2
    fixed += pad((size_t)N_NODES * 500 * 2);      // sbuf
    fixed += 5 * pad((size_t)N_NODES * 10 * 4);   // zf,t4,s4,t5,s5
    fixed += pad((size_t)tot * 2);                // bf16 input copies
    int R = 12800;
    while (R > 400 && fixed + pad((size_t)R * 2000 * 2) + 2 * pad((size_t)R * 500 * 2) > ws_size)
        R >>= 1;

    size_t off = 0;
    char* wsp = (char*)d_ws;
    auto take = [&](size_t bytes) -> void* {
        void* p = wsp + off;
        off += (bytes + 255) & ~(size_t)255;
        return p;
    };
    int*   flag      = (int*)  take(256);
    int*   row_start = (int*)  take((size_t)(N_NODES + 1) * 4);
    int*   row_fill  = (int*)  take((size_t)N_NODES * 4);
    int*   blksum    = (int*)  take(1024);
    int*   csr_col   = (int*)  take((size_t)N_EDGES * 4);
    bf16*  csr_val   = (bf16*) take((size_t)N_EDGES * 2);
    bf16*  h2    = (bf16*) take((size_t)N_NODES * 500 * 2);
    bf16*  sbuf  = (bf16*) take((size_t)N_NODES * 500 * 2);
    float* zf  = (float*)take((size_t)N_NODES * 10 * 4);
    float* t4  = (float*)take((size_t)N_NODES * 10 * 4);
    float* s4  = (float*)take((size_t)N_NODES * 10 * 4);
    float* t5  = (float*)take((size_t)N_NODES * 10 * 4);
    float* s5  = (float*)take((size_t)N_NODES * 10 * 4);
    bf16*  wcvt  = (bf16*) take((size_t)tot * 2);
    bf16*  c2000 = (bf16*) take((size_t)R * 2000 * 2);
    bf16*  d2c   = (bf16*) take((size_t)R * 500 * 2);
    bf16*  d3c   = (bf16*) take((size_t)R * 500 * 2);
    if (off > ws_size) {
        canary_kernel<<<1, 64, 0, stream>>>(outB, (float)(ws_size >> 20));
        return;
    }

    // converted input pointers
    const bf16* xb      = wcvt + cd.pre[0];
    const bf16* enc1_w  = wcvt + cd.pre[1],  *enc1_b = wcvt + cd.pre[2];
    const bf16* enc2_w  = wcvt + cd.pre[3],  *enc2_b = wcvt + cd.pre[4];
    const bf16* enc3_w  = wcvt + cd.pre[5],  *enc3_b = wcvt + cd.pre[6];
    const bf16* z_w     = wcvt + cd.pre[7],  *z_b    = wcvt + cd.pre[8];
    const bf16* dec1_w  = wcvt + cd.pre[9],  *dec1_b = wcvt + cd.pre[10];
    const bf16* dec2_w  = wcvt + cd.pre[11], *dec2_b = wcvt + cd.pre[12];
    const bf16* dec3_w  = wcvt + cd.pre[13], *dec3_b = wcvt + cd.pre[14];
    const bf16* xbar_w  = wcvt + cd.pre[15], *xbar_b = wcvt + cd.pre[16];
    const bf16* g1_w    = wcvt + cd.pre[17];
    const bf16* g2_w    = wcvt + cd.pre[18];
    const bf16* g3_w    = wcvt + cd.pre[19];
    const bf16* g4_w    = wcvt + cd.pre[20];
    const bf16* g5_w    = wcvt + cd.pre[21];
    const bf16* cluster = wcvt + cd.pre[22];

    dim3 blk(256);
    auto cdiv = [](int a, int b) { return (a + b - 1) / b; };

    // ---- detect dtype, convert inputs, build CSR
    detect_kernel<<<1, 64, 0, stream>>>((const unsigned int*)avals, flag);
    cvt_all<<<4096, blk, 0, stream>>>(cd, wcvt, flag, (long)tot);
    hipMemsetAsync(row_fill, 0, (size_t)N_NODES * 4, stream);
    hist_kernel<<<cdiv(N_EDGES, 256), blk, 0, stream>>>(arows, row_fill, N_EDGES);
    int nb = cdiv(N_NODES, 1024);   // 98
    scan1_kernel<<<nb, 1024, 0, stream>>>(row_fill, row_start, blksum, N_NODES);
    scan2_kernel<<<1, 128, 0, stream>>>(blksum, nb, row_start + N_NODES);
    scan3_kernel<<<nb, 1024, 0, stream>>>(row_start, blksum, row_fill, N_NODES);
    scatter_kernel<<<cdiv(N_EDGES, 256), blk, 0, stream>>>(arows, acols, avals, row_fill,
                                                           csr_col, csr_val, flag, N_EDGES);

    dim3 g500(cdiv(500, 128), cdiv(N_NODES, 128));

    // ---- AE encoder (h1 in cbuf; h2 in ws; h3 deferred to layer-4 loop)
    gemm_kernel<<<g500, blk, 0, stream>>>(xb,   enc1_w, cbuf, nullptr, enc1_b, nullptr, flag, N_NODES, 500, 500, 1);
    gemm_kernel<<<g500, blk, 0, stream>>>(cbuf, enc2_w, h2,   nullptr, enc2_b, nullptr, flag, N_NODES, 500, 500, 1);

    // ---- GNN layers 1-3 (spmm commuted before GEMM; combine fused in-place)
    spmm500_kernel<<<cdiv(N_NODES, 4), blk, 0, stream>>>(row_start, csr_col, csr_val, xb, sbuf, N_NODES);
    gemm_kernel<<<g500, blk, 0, stream>>>(sbuf, g1_w, cbuf, nullptr, nullptr, cbuf, flag, N_NODES, 500, 500, 1);
    spmm500_kernel<<<cdiv(N_NODES, 4), blk, 0, stream>>>(row_start, csr_col, csr_val, cbuf, sbuf, N_NODES);
    gemm_kernel<<<g500, blk, 0, stream>>>(sbuf, g2_w, cbuf, nullptr, nullptr, h2, flag, N_NODES, 500, 500, 1);
    spmm500_kernel<<<cdiv(N_NODES, 4), blk, 0, stream>>>(row_start, csr_col, csr_val, cbuf, sbuf, N_NODES);

    // ---- layer 4, chunked: h3c -> z chunk; c4c (in-place comb) -> t4 chunk
    for (int r0 = 0; r0 < N_NODES; r0 += R) {
        int mr = N_NODES - r0; if (mr > R) mr = R;
        dim3 gch(cdiv(2000, 128), cdiv(mr, 128));
        gemm_kernel<<<gch, blk, 0, stream>>>(h2 + (size_t)r0 * 500, enc3_w, c2000, nullptr, enc3_b,
                                             nullptr, flag, mr, 500, 2000, 1);
        rowgemm10_kernel<<<cdiv(mr, 4), blk, 0, stream>>>(c2000, z_w, z_b, zf + (size_t)r0 * 10,
                                             outB + oz + (size_t)r0 * 10, outF + oz + (size_t)r0 * 10,
                                             flag, mr, 2000);
        gemm_kernel<<<gch, blk, 0, stream>>>(sbuf + (size_t)r0 * 500, g3_w, c2000, nullptr, nullptr,
                                             c2000, flag, mr, 500, 2000, 1);
        rowgemm10_kernel<<<cdiv(mr, 4), blk, 0, stream>>>(c2000, g4_w, nullptr, t4 + (size_t)r0 * 10,
                                             nullptr, nullptr, flag, mr, 2000);
    }

    // ---- GNN tail
    spmm10_kernel<<<cdiv(N_NODES, 4), blk, 0, stream>>>(row_start, csr_col, csr_val, t4, s4, N_NODES);
    t5_kernel<<<cdiv(N_NODES, 256), blk, 0, stream>>>(s4, zf, g5_w, t5, N_NODES);
    spmm10_kernel<<<cdiv(N_NODES, 4), blk, 0, stream>>>(row_start, csr_col, csr_val, t5, s5, N_NODES);
    softmax10_kernel<<<cdiv(N_NODES, 256), blk, 0, stream>>>(s5, outB + op, outF + op, flag, N_NODES);
    q_kernel<<<cdiv(N_NODES, 256), blk, 0, stream>>>(zf, cluster, outB + oq, outF + oq, flag, N_NODES);

    // ---- AE decoder, chunked; writes x_bar into out (cbuf dead now)
    for (int r0 = 0; r0 < N_NODES; r0 += R) {
        int mr = N_NODES - r0; if (mr > R) mr = R;
        dim3 gc5(cdiv(500, 128), cdiv(mr, 128));
        dec1_kernel<<<dim3(mr, 2), blk, 0, stream>>>(zf, dec1_w, dec1_b, c2000, r0, 2000);
        gemm_kernel<<<gc5, blk, 0, stream>>>(c2000, dec2_w, d2c, nullptr, dec2_b, nullptr, flag, mr, 2000, 500, 1);
        gemm_kernel<<<gc5, blk, 0, stream>>>(d2c, dec3_w, d3c, nullptr, dec3_b, nullptr, flag, mr, 500, 500, 1);
        gemm_kernel<<<gc5, blk, 0, stream>>>(d3c, xbar_w, outB + (size_t)r0 * 500,
                                             outF + (size_t)r0 * 500, xbar_b,
                                             nullptr, flag, mr, 500, 500, 0);
    }
}

// Round 2
// 6518.317 us; speedup vs baseline: 1.5209x; 1.3913x over previous
//
#include <hip/hip_runtime.h>

typedef __bf16 bf16;
typedef __attribute__((ext_vector_type(8))) __bf16 bf16x8;
typedef __attribute__((ext_vector_type(4))) __bf16 bf16x4;
typedef __attribute__((ext_vector_type(4))) float f32x4;

#define N_NODES 100000
#define N_EDGES 3200000

struct CvtDesc {
    const void* src[23];
    unsigned long long pre[24];
};

// ------------------------------------------------ input dtype detection
// adj_vals = uniform[0,1/32] >= 0. bf16-packed: bit15 of each u32 word is a
// sign bit == 0. fp32: bit15 is a random mantissa bit. Any set bit -> fp32.
__global__ void detect_kernel(const unsigned int* __restrict__ w, int* flag) {
    unsigned int v = w[threadIdx.x];                 // 64 threads, one wave
    unsigned long long b = __ballot(((v >> 15) & 1u) != 0u);
    if (threadIdx.x == 0) flag[0] = (b != 0ull) ? 1 : 0;
}

// ------------------------------------- convert/copy float inputs to bf16 (22 arrays, x excluded)
__global__ __launch_bounds__(256) void cvt_all(CvtDesc d, bf16* __restrict__ dst,
                                               const int* __restrict__ flag, long total) {
    int f = *flag;
    for (long i = (long)blockIdx.x * 256 + threadIdx.x; i < total; i += (long)gridDim.x * 256) {
        int lo = 0, hi = 21;
        while (lo < hi) { int mid = (lo + hi + 1) >> 1; if (i >= (long)d.pre[mid]) lo = mid; else hi = mid - 1; }
        long k = i - (long)d.pre[lo];
        if (f) dst[i] = (bf16)((const float*)d.src[lo])[k];
        else   dst[i] = ((const bf16*)d.src[lo])[k];
    }
}

// ---- x -> xpad [N][512] bf16, zero-padded cols 500..511
__global__ __launch_bounds__(256) void cvt_x(const void* __restrict__ xsrc, bf16* __restrict__ xpad,
                                             const int* __restrict__ flag) {
    int f = *flag;
    long total = (long)N_NODES * 64;     // groups of 8 elems
    for (long i = (long)blockIdx.x * 256 + threadIdx.x; i < total; i += (long)gridDim.x * 256) {
        long row = i >> 6; int col0 = (int)(i & 63) * 8;
        bf16x8 v;
#pragma unroll
        for (int j = 0; j < 8; j++) {
            int col = col0 + j;
            bf16 x = (bf16)0.f;
            if (col < 500) {
                long k = row * 500 + col;
                x = f ? (bf16)((const float*)xsrc)[k] : ((const bf16*)xsrc)[k];
            }
            v[j] = x;
        }
        *(bf16x8*)(xpad + i * 8) = v;
    }
}

// ---- weight transpose+pad: in [K][N] -> out [Npad][Kpad], zero-padded
__global__ __launch_bounds__(256) void transpose_pad(const bf16* __restrict__ in, bf16* __restrict__ out,
                                                     int K, int N, int Kpad, int Npad)
{
    __shared__ bf16 t[32][33];
    int k0 = blockIdx.x * 32, n0 = blockIdx.y * 32;
    int tx = threadIdx.x & 31, ty = threadIdx.x >> 5;   // 32 x 8
#pragma unroll
    for (int r = 0; r < 32; r += 8) {
        int k = k0 + ty + r, n = n0 + tx;
        t[ty + r][tx] = (k < K && n < N) ? in[(long)k * N + n] : (bf16)0.f;
    }
    __syncthreads();
#pragma unroll
    for (int r = 0; r < 32; r += 8) {
        int n = n0 + ty + r, k = k0 + tx;
        if (n < Npad && k < Kpad) out[(long)n * Kpad + k] = t[tx][ty + r];
    }
}

// ---------------------------------------------------------------- CSR build
__global__ void hist_kernel(const int* __restrict__ rows, int* __restrict__ cnt, int E) {
    int e = blockIdx.x * 256 + threadIdx.x;
    if (e < E) atomicAdd(&cnt[rows[e]], 1);
}

// device-wide exclusive scan, 3 kernels (n = 100000 -> 98 blocks of 1024)
__global__ __launch_bounds__(1024) void scan1_kernel(const int* __restrict__ cnt,
                                                     int* __restrict__ excl,
                                                     int* __restrict__ blksum, int n) {
    __shared__ int wsum[16];
    int tid = threadIdx.x;
    int i = blockIdx.x * 1024 + tid;
    int lane = tid & 63, w = tid >> 6;
    int v = (i < n) ? cnt[i] : 0;
    int x = v;
#pragma unroll
    for (int off = 1; off < 64; off <<= 1) {
        int t = __shfl_up(x, off);
        if (lane >= off) x += t;
    }
    if (lane == 63) wsum[w] = x;
    __syncthreads();
    if (w == 0 && lane < 16) {
        int s = wsum[lane];
#pragma unroll
        for (int off = 1; off < 16; off <<= 1) {
            int t = __shfl_up(s, off);
            if (lane >= off) s += t;
        }
        wsum[lane] = s;
    }
    __syncthreads();
    int base = (w > 0) ? wsum[w - 1] : 0;
    int incl = base + x;
    if (i < n) excl[i] = incl - v;
    if (tid == 1023) blksum[blockIdx.x] = incl;
}

__global__ __launch_bounds__(128) void scan2_kernel(int* __restrict__ blksum, int nb,
                                                    int* __restrict__ totalp) {
    __shared__ int sh[128];
    int tid = threadIdx.x;
    int v = (tid < nb) ? blksum[tid] : 0;
    sh[tid] = v;
    __syncthreads();
    for (int off = 1; off < 128; off <<= 1) {
        int t = (tid >= off) ? sh[tid - off] : 0;
        __syncthreads();
        sh[tid] += t;
        __syncthreads();
    }
    if (tid < nb) blksum[tid] = sh[tid] - v;   // exclusive
    if (tid == 127) *totalp = sh[127];
}

__global__ __launch_bounds__(1024) void scan3_kernel(int* __restrict__ row_start,
                                                     const int* __restrict__ blksum,
                                                     int* __restrict__ fill, int n) {
    int i = blockIdx.x * 1024 + threadIdx.x;
    if (i < n) {
        int r = row_start[i] + blksum[blockIdx.x];
        row_start[i] = r;
        fill[i] = r;
    }
}

__global__ void scatter_kernel(const int* __restrict__ rows, const int* __restrict__ cols,
                               const void* __restrict__ vals, int* __restrict__ fill,
                               int* __restrict__ csr_col, bf16* __restrict__ csr_val,
                               const int* __restrict__ flag, int E) {
    int e = blockIdx.x * 256 + threadIdx.x;
    if (e < E) {
        int r = rows[e];
        int p = atomicAdd(&fill[r], 1);
        csr_col[p] = cols[e];
        float v = (*flag) ? ((const float*)vals)[e] : (float)((const bf16*)vals)[e];
        csr_val[p] = (bf16)v;
    }
}

// ------------------------------------------------------------ MFMA bf16 GEMM
// C = act(A @ Bt^T + bias); A: [M][lda] (zero-padded K region), Bt: [Npad][K]
// (pre-transposed weights, zero-padded). K must be a multiple of 32.
// Optional combine 0.5*val + 0.5*comb (comb stride = ldc, may alias C).
// If Cf != null and *flagp: store fp32 to Cf instead of bf16 to C.
__global__ __launch_bounds__(256) void gemm_kernel(
    const bf16* __restrict__ A, const bf16* __restrict__ Bt,
    bf16* C, float* Cf, const bf16* __restrict__ bias, const bf16* comb,
    const int* __restrict__ flagp, int M, int K, int N, int lda, int ldc, int do_relu)
{
    __shared__ bf16 As[128][40];
    __shared__ bf16 Bs[128][40];

    int tid  = threadIdx.x;
    int lane = tid & 63;
    int wave = tid >> 6;
    int wm = (wave >> 1) * 64;
    int wn = (wave & 1) * 64;
    int lm = lane & 15;
    int k8 = (lane >> 4) * 8;
    long row0 = (long)blockIdx.y * 128;
    int  col0 = blockIdx.x * 128;

    // staging coords: thread covers (m0,kc) and (m0+64,kc), kc in {0,8,16,24}
    int m0 = tid >> 2, kc = (tid & 3) << 3;
    int m1 = m0 + 64;
    long gm0 = row0 + m0; if (gm0 > M - 1) gm0 = M - 1;   // clamp; masked at store
    long gm1 = row0 + m1; if (gm1 > M - 1) gm1 = M - 1;
    const bf16* pA0 = A + gm0 * (long)lda + kc;
    const bf16* pA1 = A + gm1 * (long)lda + kc;
    const bf16* pB0 = Bt + (long)(col0 + m0) * K + kc;    // Npad >= col0+128 always
    const bf16* pB1 = Bt + (long)(col0 + m1) * K + kc;

    f32x4 zero4 = {0.f, 0.f, 0.f, 0.f};
    f32x4 acc[4][4];
#pragma unroll
    for (int i = 0; i < 4; i++)
#pragma unroll
        for (int j = 0; j < 4; j++) acc[i][j] = zero4;

    for (int k0 = 0; k0 < K; k0 += 32) {
        bf16x8 a0 = *(const bf16x8*)(pA0 + k0);
        bf16x8 b0 = *(const bf16x8*)(pB0 + k0);
        bf16x8 a1 = *(const bf16x8*)(pA1 + k0);
        bf16x8 b1 = *(const bf16x8*)(pB1 + k0);
        union { bf16x8 v; unsigned long long q[2]; } ua0, ua1, ub0, ub1;
        ua0.v = a0; ua1.v = a1; ub0.v = b0; ub1.v = b1;
        *(unsigned long long*)&As[m0][kc]     = ua0.q[0];
        *(unsigned long long*)&As[m0][kc + 4] = ua0.q[1];
        *(unsigned long long*)&As[m1][kc]     = ua1.q[0];
        *(unsigned long long*)&As[m1][kc + 4] = ua1.q[1];
        *(unsigned long long*)&Bs[m0][kc]     = ub0.q[0];
        *(unsigned long long*)&Bs[m0][kc + 4] = ub0.q[1];
        *(unsigned long long*)&Bs[m1][kc]     = ub1.q[0];
        *(unsigned long long*)&Bs[m1][kc + 4] = ub1.q[1];
        __syncthreads();

        bf16x8 af[4], bfr[4];
#pragma unroll
        for (int i = 0; i < 4; i++) af[i]  = *(const bf16x8*)&As[wm + i * 16 + lm][k8];
#pragma unroll
        for (int j = 0; j < 4; j++) bfr[j] = *(const bf16x8*)&Bs[wn + j * 16 + lm][k8];
#pragma unroll
        for (int i = 0; i < 4; i++)
#pragma unroll
            for (int j = 0; j < 4; j++)
                acc[i][j] = __builtin_amdgcn_mfma_f32_16x16x32_bf16(af[i], bfr[j], acc[i][j], 0, 0, 0);
        __syncthreads();
    }

    int f32o = (Cf != nullptr) && (*flagp != 0);
#pragma unroll
    for (int i = 0; i < 4; i++) {
#pragma unroll
        for (int r = 0; r < 4; r++) {
            long row = row0 + wm + i * 16 + (lane >> 4) * 4 + r;
            if (row < M) {
#pragma unroll
                for (int j = 0; j < 4; j++) {
                    int col = col0 + wn + j * 16 + lm;
                    if (col < N) {
                        float v = acc[i][j][r];
                        if (bias) v += (float)bias[col];
                        if (do_relu) v = fmaxf(v, 0.f);
                        if (comb) v = 0.5f * v + 0.5f * (float)comb[row * (long)ldc + col];
                        if (f32o) Cf[row * (long)ldc + col] = v;
                        else      C [row * (long)ldc + col] = (bf16)v;
                    }
                }
            }
        }
    }
}

// ----------------------------------------------------- spmm, 512-stride bf16
// one row per WAVE: lane l owns elems 8l..8l+7 (covers all 512 cols exactly).
// One bf16x8 (16B) load per edge per lane; 8-edge groups -> 8 KB in flight/wave.
// Input pads (cols 500..511) are zero, so output pads are zero too.
#define SP_EDGE(u, Lv, Vv) \
    { int c_ = __shfl(cl, j + u); Vv = __shfl(vl, j + u); \
      Lv = *(const bf16x8*)(Min + (long)c_ * 512 + o); }
#define SP_FMA(Lv, Vv) \
    _Pragma("unroll") \
    for (int q = 0; q < 8; q++) acc[q] += Vv * (float)Lv[q];

__global__ __launch_bounds__(256) void spmm500_kernel(
    const int* __restrict__ row_start, const int* __restrict__ csr_col,
    const bf16* __restrict__ csr_val, const bf16* __restrict__ Min,
    bf16* __restrict__ Mout, int n_rows)
{
    int wave = threadIdx.x >> 6, lane = threadIdx.x & 63;
    int row = blockIdx.x * 4 + wave;
    if (row >= n_rows) return;
    int s = row_start[row], e = row_start[row + 1];
    int o = lane * 8;

    float acc[8];
#pragma unroll
    for (int q = 0; q < 8; q++) acc[q] = 0.f;

    for (int base = s; base < e; base += 64) {
        int idx = base + lane;
        int   cl = (idx < e) ? csr_col[idx] : 0;
        float vl = (idx < e) ? (float)csr_val[idx] : 0.f;   // OOB edges: v=0, c=0 (harmless)
        int cnt = e - base; if (cnt > 64) cnt = 64;
        for (int j = 0; j < cnt; j += 8) {
            bf16x8 L0, L1, L2, L3, L4, L5, L6, L7;
            float V0, V1, V2, V3, V4, V5, V6, V7;
            SP_EDGE(0, L0, V0) SP_EDGE(1, L1, V1) SP_EDGE(2, L2, V2) SP_EDGE(3, L3, V3)
            SP_EDGE(4, L4, V4) SP_EDGE(5, L5, V5) SP_EDGE(6, L6, V6) SP_EDGE(7, L7, V7)
            SP_FMA(L0, V0) SP_FMA(L1, V1) SP_FMA(L2, V2) SP_FMA(L3, V3)
            SP_FMA(L4, V4) SP_FMA(L5, V5) SP_FMA(L6, V6) SP_FMA(L7, V7)
        }
    }

    bf16x8 outv;
#pragma unroll
    for (int q = 0; q < 8; q++) outv[q] = (bf16)acc[q];
    *(bf16x8*)(Mout + (long)row * 512 + o) = outv;
}

// -------------------------------------------------------- spmm, D=10 (f32 io)
__global__ __launch_bounds__(256) void spmm10_kernel(
    const int* __restrict__ row_start, const int* __restrict__ csr_col,
    const bf16* __restrict__ csr_val, const float* __restrict__ Tin,
    float* __restrict__ Tout, int n_rows)
{
    int row  = blockIdx.x * 4 + (threadIdx.x >> 6);
    int lane = threadIdx.x & 63;
    if (row >= n_rows) return;
    int s = row_start[row], e = row_start[row + 1];
    float acc[10];
#pragma unroll
    for (int d = 0; d < 10; d++) acc[d] = 0.f;
    for (int i = s + lane; i < e; i += 64) {
        int c = csr_col[i];
        float v = (float)csr_val[i];
        const float2* tr = (const float2*)(Tin + (long)c * 10);   // 8B-aligned (c*40)
        float2 p0 = tr[0], p1 = tr[1], p2 = tr[2], p3 = tr[3], p4 = tr[4];
        acc[0] += v * p0.x; acc[1] += v * p0.y;
        acc[2] += v * p1.x; acc[3] += v * p1.y;
        acc[4] += v * p2.x; acc[5] += v * p2.y;
        acc[6] += v * p3.x; acc[7] += v * p3.y;
        acc[8] += v * p4.x; acc[9] += v * p4.y;
    }
#pragma unroll
    for (int off = 32; off; off >>= 1)
#pragma unroll
        for (int d = 0; d < 10; d++) acc[d] += __shfl_down(acc[d], off);
    if (lane == 0) {
#pragma unroll
        for (int d = 0; d < 10; d++) Tout[(long)row * 10 + d] = acc[d];
    }
}

// --------------------------------- A[M,K](bf16,stride lda) @ W[K,10](bf16)
__global__ __launch_bounds__(256) void rowgemm10_kernel(
    const bf16* __restrict__ A, const bf16* __restrict__ W,
    const bf16* __restrict__ bias, float* outf, bf16* outb, float* outbf,
    const int* __restrict__ flagp, int n_rows, int K, int lda)
{
    int row  = blockIdx.x * 4 + (threadIdx.x >> 6);
    int lane = threadIdx.x & 63;
    if (row >= n_rows) return;
    const bf16* a = A + (long)row * lda;
    float acc[10];
#pragma unroll
    for (int j = 0; j < 10; j++) acc[j] = 0.f;
    typedef __attribute__((ext_vector_type(2))) __bf16 bf16x2;
    for (int k = lane * 4; k + 3 < K; k += 256) {    // K % 4 == 0 (2000)
        bf16x4 av = *(const bf16x4*)(a + k);
#pragma unroll
        for (int q = 0; q < 4; q++) {
            float v = (float)av[q];
            const bf16x2* w = (const bf16x2*)(W + (long)(k + q) * 10);  // 4B-aligned
#pragma unroll
            for (int h = 0; h < 5; h++) {
                bf16x2 wp = w[h];
                acc[2 * h]     += v * (float)wp[0];
                acc[2 * h + 1] += v * (float)wp[1];
            }
        }
    }
#pragma unroll
    for (int off = 32; off; off >>= 1)
#pragma unroll
        for (int j = 0; j < 10; j++) acc[j] += __shfl_down(acc[j], off);
    if (lane == 0) {
        int f = (outb != nullptr) && (*flagp != 0);
#pragma unroll
        for (int j = 0; j < 10; j++) {
            float r = acc[j] + (bias ? (float)bias[j] : 0.f);
            if (outf) outf[(long)row * 10 + j] = r;
            if (outb) {
                if (f) outbf[(long)row * 10 + j] = r;
                else   outb [(long)row * 10 + j] = (bf16)r;
            }
        }
    }
}

// ----------------------------- d1 = relu(z[rows,10] @ W[10,2000] + b), stride ldd
__global__ void dec1_kernel(const float* __restrict__ z, const bf16* __restrict__ W,
                            const bf16* __restrict__ b, bf16* __restrict__ d1,
                            int row_off, int Dout, int ldd)
{
    int row = blockIdx.x;
    int c0 = (blockIdx.y * 256 + threadIdx.x) * 4;
    if (c0 + 3 >= Dout) return;                       // Dout % 4 == 0; pads stay 0
    const float* zr = z + (long)(row_off + row) * 10;
    bf16x4 bb = *(const bf16x4*)(b + c0);
    float acc[4];
#pragma unroll
    for (int q = 0; q < 4; q++) acc[q] = (float)bb[q];
#pragma unroll
    for (int k = 0; k < 10; k++) {
        float zv = zr[k];
        bf16x4 wv = *(const bf16x4*)(W + (long)k * Dout + c0);
#pragma unroll
        for (int q = 0; q < 4; q++) acc[q] += zv * (float)wv[q];
    }
    bf16x4 o;
#pragma unroll
    for (int q = 0; q < 4; q++) o[q] = (bf16)fmaxf(acc[q], 0.f);
    *(bf16x4*)(d1 + (long)row * ldd + c0) = o;
}

// ------------- t5 = (0.5*relu(s4) + 0.5*z) @ g5[10,10]
__global__ void t5_kernel(const float* __restrict__ s4, const float* __restrict__ z,
                          const bf16* __restrict__ g5, float* __restrict__ t5, int n)
{
    int row = blockIdx.x * 256 + threadIdx.x;
    if (row >= n) return;
    float c5[10];
#pragma unroll
    for (int k = 0; k < 10; k++)
        c5[k] = 0.5f * fmaxf(s4[(long)row * 10 + k], 0.f) + 0.5f * z[(long)row * 10 + k];
#pragma unroll
    for (int j = 0; j < 10; j++) {
        float a = 0.f;
#pragma unroll
        for (int k = 0; k < 10; k++) a += c5[k] * (float)g5[k * 10 + j];
        t5[(long)row * 10 + j] = a;
    }
}

__global__ void softmax10_kernel(const float* __restrict__ S, bf16* Pb, float* Pf,
                                 const int* __restrict__ flagp, int n) {
    int row = blockIdx.x * 256 + threadIdx.x;
    if (row >= n) return;
    float v[10];
    float m = -1e30f;
#pragma unroll
    for (int j = 0; j < 10; j++) { v[j] = S[(long)row * 10 + j]; m = fmaxf(m, v[j]); }
    float sum = 0.f;
#pragma unroll
    for (int j = 0; j < 10; j++) { v[j] = expf(v[j] - m); sum += v[j]; }
    float inv = 1.f / sum;
    int f = *flagp;
#pragma unroll
    for (int j = 0; j < 10; j++) {
        if (f) Pf[(long)row * 10 + j] = v[j] * inv;
        else   Pb[(long)row * 10 + j] = (bf16)(v[j] * inv);
    }
}

__global__ void q_kernel(const float* __restrict__ z, const bf16* __restrict__ cluster,
                         bf16* qb, float* qf, const int* __restrict__ flagp, int n) {
    int row = blockIdx.x * 256 + threadIdx.x;
    if (row >= n) return;
    float zr[10];
#pragma unroll
    for (int d = 0; d < 10; d++) zr[d] = z[(long)row * 10 + d];
    float q[10]; float s = 0.f;
#pragma unroll
    for (int k = 0; k < 10; k++) {
        float dist = 0.f;
#pragma unroll
        for (int d = 0; d < 10; d++) {
            float df = zr[d] - (float)cluster[k * 10 + d];
            dist += df * df;
        }
        q[k] = 1.f / (1.f + dist);   // v=1, exponent (v+1)/2 = 1
        s += q[k];
    }
    float inv = 1.f / s;
    int f = *flagp;
#pragma unroll
    for (int k = 0; k < 10; k++) {
        if (f) qf[(long)row * 10 + k] = q[k] * inv;
        else   qb[(long)row * 10 + k] = (bf16)(q[k] * inv);
    }
}

__global__ void canary_kernel(bf16* o, float v) {
    if (threadIdx.x == 0 && blockIdx.x == 0) o[0] = (bf16)v;
}

// ---------------------------------------------------------------------------
extern "C" void kernel_launch(void* const* d_in, const int* in_sizes, int n_in,
                              void* d_out, int out_size, void* d_ws, size_t ws_size,
                              hipStream_t stream)
{
    const void* xsrc   = d_in[0];
    const int*  arows  = (const int*)d_in[1];
    const int*  acols  = (const int*)d_in[2];
    const void* avals  = d_in[3];

    // float-input index map (weights/biases/cluster; x handled separately)
    const int fidx[22] = {4,5,6,7,8,9,10,11,12,13,14,15,16,17,18,19,20,21,22,23,24,25};
    CvtDesc cd;
    unsigned long long tot = 0;
    for (int a = 0; a < 22; a++) {
        cd.src[a] = d_in[fidx[a]];
        cd.pre[a] = tot;
        tot += (unsigned long long)in_sizes[fidx[a]];
    }
    cd.pre[22] = tot;

    // output views (element offsets identical in both dtypes)
    bf16*  outB = (bf16*)d_out;
    float* outF = (float*)d_out;
    size_t oq = (size_t)N_NODES * 500, op = oq + (size_t)N_NODES * 10, oz = op + (size_t)N_NODES * 10;
    bf16* cbuf = outB;   // [N][512] scratch in x_bar region (dead until decoder; q/p/z written later)

    const long WT_TOTAL = 6L * 512 * 512 + 2L * 2048 * 512 + 512L * 2048;

    // ---- workspace fit
    auto pad = [](size_t b) { return (b + 255) & ~(size_t)255; };
    size_t fixed = 0;
    fixed += pad(256);                            // flag
    fixed += pad((size_t)(N_NODES + 1) * 4);      // row_start
    fixed += pad((size_t)N_NODES * 4);            // row_fill
    fixed += pad(1024);                           // blksum
    fixed += pad((size_t)N_EDGES * 4);            // csr_col
    fixed += pad((size_t)N_EDGES * 2);            // csr_val
    fixed += pad((size_t)N_NODES * 512 * 2);      // h2
    fixed += pad((size_t)N_NODES * 512 * 2);      // sbuf
    fixed += pad((size_t)N_NODES * 512 * 2);      // xpad
    fixed += 5 * pad((size_t)N_NODES * 10 * 4);   // zf,t4,s4,t5,s5
    fixed += pad((size_t)tot * 2);                // bf16 weight copies
    fixed += pad((size_t)WT_TOTAL * 2);           // transposed weights
    int R = 12800;
    while (R > 400 && fixed + pad((size_t)R * 2048 * 2) + 2 * pad((size_t)R * 512 * 2) > ws_size)
        R >>= 1;

    size_t off = 0;
    char* wsp = (char*)d_ws;
    auto take = [&](size_t bytes) -> void* {
        void* p = wsp + off;
        off += (bytes + 255) & ~(size_t)255;
        return p;
    };
    int*   flag      = (int*)  take(256);
    int*   row_start = (int*)  take((size_t)(N_NODES + 1) * 4);
    int*   row_fill  = (int*)  take((size_t)N_NODES * 4);
    int*   blksum    = (int*)  take(1024);
    int*   csr_col   = (int*)  take((size_t)N_EDGES * 4);
    bf16*  csr_val   = (bf16*) take((size_t)N_EDGES * 2);
    bf16*  h2    = (bf16*) take((size_t)N_NODES * 512 * 2);
    bf16*  sbuf  = (bf16*) take((size_t)N_NODES * 512 * 2);
    bf16*  xpad  = (bf16*) take((size_t)N_NODES * 512 * 2);
    float* zf  = (float*)take((size_t)N_NODES * 10 * 4);
    float* t4  = (float*)take((size_t)N_NODES * 10 * 4);
    float* s4  = (float*)take((size_t)N_NODES * 10 * 4);
    float* t5  = (float*)take((size_t)N_NODES * 10 * 4);
    float* s5  = (float*)take((size_t)N_NODES * 10 * 4);
    bf16*  wcvt  = (bf16*) take((size_t)tot * 2);
    bf16*  wT    = (bf16*) take((size_t)WT_TOTAL * 2);
    bf16*  c2000 = (bf16*) take((size_t)R * 2048 * 2);
    bf16*  d2c   = (bf16*) take((size_t)R * 512 * 2);
    bf16*  d3c   = (bf16*) take((size_t)R * 512 * 2);
    if (off > ws_size) {
        canary_kernel<<<1, 64, 0, stream>>>(outB, (float)(ws_size >> 20));
        return;
    }

    // converted input pointers (22-array map)
    const bf16* enc1_w  = wcvt + cd.pre[0],  *enc1_b = wcvt + cd.pre[1];
    const bf16* enc2_w  = wcvt + cd.pre[2],  *enc2_b = wcvt + cd.pre[3];
    const bf16* enc3_w  = wcvt + cd.pre[4],  *enc3_b = wcvt + cd.pre[5];
    const bf16* z_w     = wcvt + cd.pre[6],  *z_b    = wcvt + cd.pre[7];
    const bf16* dec1_w  = wcvt + cd.pre[8],  *dec1_b = wcvt + cd.pre[9];
    const bf16* dec2_w  = wcvt + cd.pre[10], *dec2_b = wcvt + cd.pre[11];
    const bf16* dec3_w  = wcvt + cd.pre[12], *dec3_b = wcvt + cd.pre[13];
    const bf16* xbar_w  = wcvt + cd.pre[14], *xbar_b = wcvt + cd.pre[15];
    const bf16* g1_w    = wcvt + cd.pre[16];
    const bf16* g2_w    = wcvt + cd.pre[17];
    const bf16* g3_w    = wcvt + cd.pre[18];
    const bf16* g4_w    = wcvt + cd.pre[19];
    const bf16* g5_w    = wcvt + cd.pre[20];
    const bf16* cluster = wcvt + cd.pre[21];

    // transposed-weight views
    bf16* e1T = wT;
    bf16* e2T = e1T + 512L * 512;
    bf16* g1T = e2T + 512L * 512;
    bf16* g2T = g1T + 512L * 512;
    bf16* d3T = g2T + 512L * 512;
    bf16* xbT = d3T + 512L * 512;
    bf16* e3T = xbT + 512L * 512;      // [2048][512]
    bf16* g3T = e3T + 2048L * 512;     // [2048][512]
    bf16* d2T = g3T + 2048L * 512;     // [512][2048]

    dim3 blk(256);
    auto cdiv = [](int a, int b) { return (a + b - 1) / b; };

    // ---- detect dtype, convert inputs, zero pad regions, build CSR
    detect_kernel<<<1, 64, 0, stream>>>((const unsigned int*)avals, flag);
    cvt_all<<<2048, blk, 0, stream>>>(cd, wcvt, flag, (long)tot);
    cvt_x<<<4096, blk, 0, stream>>>(xsrc, xpad, flag);
    hipMemsetAsync(cbuf,  0, (size_t)N_NODES * 512 * 2, stream);
    hipMemsetAsync(h2,    0, (size_t)N_NODES * 512 * 2, stream);
    hipMemsetAsync(c2000, 0, (size_t)R * 2048 * 2, stream);
    hipMemsetAsync(d2c,   0, (size_t)R * 512 * 2, stream);
    hipMemsetAsync(d3c,   0, (size_t)R * 512 * 2, stream);

    // weight transposes (after cvt_all; stream-ordered)
    transpose_pad<<<dim3(16, 16), blk, 0, stream>>>(enc1_w, e1T, 500, 500, 512, 512);
    transpose_pad<<<dim3(16, 16), blk, 0, stream>>>(enc2_w, e2T, 500, 500, 512, 512);
    transpose_pad<<<dim3(16, 16), blk, 0, stream>>>(g1_w,   g1T, 500, 500, 512, 512);
    transpose_pad<<<dim3(16, 16), blk, 0, stream>>>(g2_w,   g2T, 500, 500, 512, 512);
    transpose_pad<<<dim3(16, 16), blk, 0, stream>>>(dec3_w, d3T, 500, 500, 512, 512);
    transpose_pad<<<dim3(16, 16), blk, 0, stream>>>(xbar_w, xbT, 500, 500, 512, 512);
    transpose_pad<<<dim3(16, 64), blk, 0, stream>>>(enc3_w, e3T, 500, 2000, 512, 2048);
    transpose_pad<<<dim3(16, 64), blk, 0, stream>>>(g3_w,   g3T, 500, 2000, 512, 2048);
    transpose_pad<<<dim3(64, 16), blk, 0, stream>>>(dec2_w, d2T, 2000, 500, 2048, 512);

    hipMemsetAsync(row_fill, 0, (size_t)N_NODES * 4, stream);
    hist_kernel<<<cdiv(N_EDGES, 256), blk, 0, stream>>>(arows, row_fill, N_EDGES);
    int nb = cdiv(N_NODES, 1024);   // 98
    scan1_kernel<<<nb, 1024, 0, stream>>>(row_fill, row_start, blksum, N_NODES);
    scan2_kernel<<<1, 128, 0, stream>>>(blksum, nb, row_start + N_NODES);
    scan3_kernel<<<nb, 1024, 0, stream>>>(row_start, blksum, row_fill, N_NODES);
    scatter_kernel<<<cdiv(N_EDGES, 256), blk, 0, stream>>>(arows, acols, avals, row_fill,
                                                           csr_col, csr_val, flag, N_EDGES);

    dim3 g500(4, cdiv(N_NODES, 128));

    // ---- AE encoder (h1 in cbuf; h2 in ws; h3 deferred to layer-4 loop)
    gemm_kernel<<<g500, blk, 0, stream>>>(xpad, e1T, cbuf, nullptr, enc1_b, nullptr, flag, N_NODES, 512, 500, 512, 512, 1);
    gemm_kernel<<<g500, blk, 0, stream>>>(cbuf, e2T, h2,   nullptr, enc2_b, nullptr, flag, N_NODES, 512, 500, 512, 512, 1);

    // ---- GNN layers 1-3 (spmm commuted before GEMM; combine fused in-place)
    spmm500_kernel<<<cdiv(N_NODES, 4), blk, 0, stream>>>(row_start, csr_col, csr_val, xpad, sbuf, N_NODES);
    gemm_kernel<<<g500, blk, 0, stream>>>(sbuf, g1T, cbuf, nullptr, nullptr, cbuf, flag, N_NODES, 512, 500, 512, 512, 1);
    spmm500_kernel<<<cdiv(N_NODES, 4), blk, 0, stream>>>(row_start, csr_col, csr_val, cbuf, sbuf, N_NODES);
    gemm_kernel<<<g500, blk, 0, stream>>>(sbuf, g2T, cbuf, nullptr, nullptr, h2, flag, N_NODES, 512, 500, 512, 512, 1);
    spmm500_kernel<<<cdiv(N_NODES, 4), blk, 0, stream>>>(row_start, csr_col, csr_val, cbuf, sbuf, N_NODES);

    // ---- layer 4, chunked: h3c -> z chunk; c4c (in-place comb) -> t4 chunk
    for (int r0 = 0; r0 < N_NODES; r0 += R) {
        int mr = N_NODES - r0; if (mr > R) mr = R;
        dim3 gch(16, cdiv(mr, 128));
        gemm_kernel<<<gch, blk, 0, stream>>>(h2 + (size_t)r0 * 512, e3T, c2000, nullptr, enc3_b,
                                             nullptr, flag, mr, 512, 2000, 512, 2048, 1);
        rowgemm10_kernel<<<cdiv(mr, 4), blk, 0, stream>>>(c2000, z_w, z_b, zf + (size_t)r0 * 10,
                                             outB + oz + (size_t)r0 * 10, outF + oz + (size_t)r0 * 10,
                                             flag, mr, 2000, 2048);
        gemm_kernel<<<gch, blk, 0, stream>>>(sbuf + (size_t)r0 * 512, g3T, c2000, nullptr, nullptr,
                                             c2000, flag, mr, 512, 2000, 512, 2048, 1);
        rowgemm10_kernel<<<cdiv(mr, 4), blk, 0, stream>>>(c2000, g4_w, nullptr, t4 + (size_t)r0 * 10,
                                             nullptr, nullptr, flag, mr, 2000, 2048);
    }

    // ---- GNN tail
    spmm10_kernel<<<cdiv(N_NODES, 4), blk, 0, stream>>>(row_start, csr_col, csr_val, t4, s4, N_NODES);
    t5_kernel<<<cdiv(N_NODES, 256), blk, 0, stream>>>(s4, zf, g5_w, t5, N_NODES);
    spmm10_kernel<<<cdiv(N_NODES, 4), blk, 0, stream>>>(row_start, csr_col, csr_val, t5, s5, N_NODES);
    softmax10_kernel<<<cdiv(N_NODES, 256), blk, 0, stream>>>(s5, outB + op, outF + op, flag, N_NODES);
    q_kernel<<<cdiv(N_NODES, 256), blk, 0, stream>>>(zf, cluster, outB + oq, outF + oq, flag, N_NODES);

    // ---- AE decoder, chunked; writes x_bar into out (cbuf dead now)
    for (int r0 = 0; r0 < N_NODES; r0 += R) {
        int mr = N_NODES - r0; if (mr > R) mr = R;
        dim3 gc5(4, cdiv(mr, 128));
        dec1_kernel<<<dim3(mr, 2), blk, 0, stream>>>(zf, dec1_w, dec1_b, c2000, r0, 2000, 2048);
        gemm_kernel<<<gc5, blk, 0, stream>>>(c2000, d2T, d2c, nullptr, dec2_b, nullptr, flag, mr, 2048, 500, 2048, 512, 1);
        gemm_kernel<<<gc5, blk, 0, stream>>>(d2c, d3T, d3c, nullptr, dec3_b, nullptr, flag, mr, 512, 500, 512, 512, 1);
        gemm_kernel<<<gc5, blk, 0, stream>>>(d3c, xbT, outB + (size_t)r0 * 500,
                                             outF + (size_t)r0 * 500, xbar_b,
                                             nullptr, flag, mr, 512, 500, 512, 500, 0);
    }
}